// Round 1
// baseline (703.509 us; speedup 1.0000x reference)
//
#include <hip/hip_runtime.h>

// Grid2Mesh: edge MLP (E=262144, K=384) + gather-mean (K=32) + node MLP (K=256)
// + grid MLP (NG=65536, K=128), all with tanh + layernorm + residual.
// Strategy: bf16 MFMA (16x16x32) for all matmuls; delta_edge stored bf16 in ws.

typedef __bf16 bf16x8 __attribute__((ext_vector_type(8)));
typedef float f32x4 __attribute__((ext_vector_type(4)));

#define E_CNT  262144
#define NG_CNT 65536
#define NM_CNT 8192

__device__ __forceinline__ float fast_tanh(float x) {
    // tanh(x) = 1 - 2/(1+e^{2x}); saturates correctly at +-inf
    float e = __expf(2.0f * x);
    return 1.0f - 2.0f / (1.0f + e);
}
__device__ __forceinline__ unsigned short bfbits(float f) {
    __bf16 h = (__bf16)f;
    return __builtin_bit_cast(unsigned short, h);
}
__device__ __forceinline__ __bf16 bf(float f) { return (__bf16)f; }

// MODE 0: A = concat(gm_be[e], rect[src[e]], mesh[dst[e]])  (f32 gather, KDIM=384)
// MODE 1: A = precomputed bf16 rows (KDIM=256)
// MODE 2: A = contiguous f32 rows (KDIM=128)
template <int KDIM, int MODE, bool STORE_DELTA>
__global__ __launch_bounds__(1024, 4) void mlp_kernel(
    const float* __restrict__ A0, const float* __restrict__ A1,
    const float* __restrict__ A2, const int* __restrict__ pair,
    const unsigned short* __restrict__ Abf, const float* __restrict__ W,
    const float* __restrict__ gvec, const float* __restrict__ bvec,
    const float* __restrict__ resid, float* __restrict__ out,
    unsigned short* __restrict__ delta_out, int M) {
    constexpr int KPAD = KDIM + 8;  // +8 bf16 pad -> 2-way-max LDS bank aliasing (free)
    __shared__ unsigned short wt[128 * KPAD];  // W^T[n][k], bf16

    const int tid = threadIdx.x;
    for (int i = tid; i < KDIM * 128; i += blockDim.x) {
        int k = i >> 7, n = i & 127;
        wt[n * KPAD + k] = bfbits(W[i]);
    }
    __syncthreads();

    const int lane = tid & 63;
    const int wid = tid >> 6;
    const int r = lane & 15;
    const int quad = lane >> 4;

    float gr[8], br[8];
#pragma unroll
    for (int n = 0; n < 8; ++n) {
        gr[n] = gvec[n * 16 + r];
        br[n] = bvec[n * 16 + r];
    }

    const unsigned short* wl = wt + r * KPAD + quad * 8;

    const int totalWaves = (gridDim.x * blockDim.x) >> 6;
    const int tiles = M >> 4;
    const int wavesPerBlock = blockDim.x >> 6;

    for (int t = blockIdx.x * wavesPerBlock + wid; t < tiles; t += totalWaves) {
        const int row16 = t << 4;
        f32x4 acc[8] = {};

        const float* pseg[3];
        const unsigned short* pb = nullptr;
        if (MODE == 0) {
            int e = row16 + r;
            int s = pair[2 * e], d2 = pair[2 * e + 1];
            pseg[0] = A0 + (size_t)e * 128;
            pseg[1] = A1 + (size_t)s * 128;
            pseg[2] = A2 + (size_t)d2 * 128;
        } else if (MODE == 1) {
            pb = Abf + (size_t)(row16 + r) * KDIM + quad * 8;
        } else {
            pseg[0] = A0 + (size_t)(row16 + r) * 128;
            pseg[1] = pseg[0];
            pseg[2] = pseg[0];
        }

#pragma unroll
        for (int kk = 0; kk < KDIM / 32; ++kk) {
            bf16x8 a;
            if (MODE == 1) {
                a = *(const bf16x8*)(pb + kk * 32);
            } else {
                const int seg = (MODE == 0) ? (kk >> 2) : 0;
                const float* p = pseg[seg] + (kk & 3) * 32 + quad * 8;
                f32x4 f0 = *(const f32x4*)p;
                f32x4 f1 = *(const f32x4*)(p + 4);
#pragma unroll
                for (int j = 0; j < 4; ++j) {
                    a[j] = bf(f0[j]);
                    a[4 + j] = bf(f1[j]);
                }
            }
#pragma unroll
            for (int n = 0; n < 8; ++n) {
                bf16x8 bb = *(const bf16x8*)(wl + n * 16 * KPAD + kk * 32);
                acc[n] = __builtin_amdgcn_mfma_f32_16x16x32_bf16(a, bb, acc[n], 0, 0, 0);
            }
        }

        // tanh + layernorm. C/D layout: col = n*16 + (lane&15), row = 4*quad + reg.
        float tv[8][4];
#pragma unroll
        for (int n = 0; n < 8; ++n)
#pragma unroll
            for (int j = 0; j < 4; ++j) tv[n][j] = fast_tanh(acc[n][j]);

        float s1[4] = {0, 0, 0, 0}, s2[4] = {0, 0, 0, 0};
#pragma unroll
        for (int j = 0; j < 4; ++j)
#pragma unroll
            for (int n = 0; n < 8; ++n) {
                s1[j] += tv[n][j];
                s2[j] += tv[n][j] * tv[n][j];
            }
#pragma unroll
        for (int m = 1; m < 16; m <<= 1) {
#pragma unroll
            for (int j = 0; j < 4; ++j) {
                s1[j] += __shfl_xor(s1[j], m, 64);
                s2[j] += __shfl_xor(s2[j], m, 64);
            }
        }
        float mu[4], rs[4];
#pragma unroll
        for (int j = 0; j < 4; ++j) {
            mu[j] = s1[j] * (1.0f / 128.0f);
            float var = s2[j] * (1.0f / 128.0f) - mu[j] * mu[j];
            rs[j] = rsqrtf(var + 1e-5f);
        }

        const int orow = row16 + quad * 4;
#pragma unroll
        for (int j = 0; j < 4; ++j) {
            const size_t rb = (size_t)(orow + j) * 128;
#pragma unroll
            for (int n = 0; n < 8; ++n) {
                const int c = n * 16 + r;
                float d = (tv[n][j] - mu[j]) * rs[j] * gr[n] + br[n];
                out[rb + c] = resid[rb + c] + d;
                if (STORE_DELTA) delta_out[rb + c] = bfbits(d);
            }
        }
    }
}

// Aggregation: x2[n] = concat(bf16(mesh[n]), bf16(mean_k coef*delta[eid[n][k]]))
template <bool FROM_WS>
__global__ __launch_bounds__(256) void agg_kernel(
    const unsigned short* __restrict__ dws, const float* __restrict__ out0,
    const float* __restrict__ gm, const float* __restrict__ mesh,
    const int* __restrict__ eid, const float* __restrict__ coef,
    unsigned short* __restrict__ x2) {
    __shared__ int eid_s[512];
    __shared__ float cf_s[512];
    const int t = threadIdx.x;
    const int n0 = blockIdx.x * 16;
    for (int i = t; i < 512; i += 256) {
        eid_s[i] = eid[n0 * 32 + i];
        cf_s[i] = coef[n0 * 32 + i];
    }
    __syncthreads();

    const int rl = t >> 4;
    const int d8 = (t & 15) * 8;  // 16 threads cover a full 256B row -> coalesced gather
    const int row = n0 + rl;

    float acc[8] = {0, 0, 0, 0, 0, 0, 0, 0};
    for (int k = 0; k < 32; ++k) {
        const int e = eid_s[rl * 32 + k];
        const float cf = cf_s[rl * 32 + k];
        if (FROM_WS) {
            bf16x8 v = *(const bf16x8*)(dws + (size_t)e * 128 + d8);
#pragma unroll
            for (int j = 0; j < 8; ++j) acc[j] += cf * (float)v[j];
        } else {
            const float* po = out0 + (size_t)e * 128 + d8;
            const float* pg = gm + (size_t)e * 128 + d8;
            f32x4 o0 = *(const f32x4*)po, o1 = *(const f32x4*)(po + 4);
            f32x4 g0 = *(const f32x4*)pg, g1 = *(const f32x4*)(pg + 4);
#pragma unroll
            for (int j = 0; j < 4; ++j) {
                acc[j] += cf * (o0[j] - g0[j]);
                acc[4 + j] += cf * (o1[j] - g1[j]);
            }
        }
    }

    const float* pm = mesh + (size_t)row * 128 + d8;
    f32x4 m0 = *(const f32x4*)pm, m1 = *(const f32x4*)(pm + 4);
    bf16x8 mv, av;
#pragma unroll
    for (int j = 0; j < 4; ++j) {
        mv[j] = bf(m0[j]);
        mv[4 + j] = bf(m1[j]);
    }
#pragma unroll
    for (int j = 0; j < 8; ++j) av[j] = bf(acc[j] * (1.0f / 32.0f));
    *(bf16x8*)(x2 + (size_t)row * 256 + d8) = mv;
    *(bf16x8*)(x2 + (size_t)row * 256 + 128 + d8) = av;
}

extern "C" void kernel_launch(void* const* d_in, const int* in_sizes, int n_in,
                              void* d_out, int out_size, void* d_ws,
                              size_t ws_size, hipStream_t stream) {
    const float* gm = (const float*)d_in[0];
    const float* rect = (const float*)d_in[1];
    const float* mesh = (const float*)d_in[2];
    const int* pair = (const int*)d_in[3];
    const int* eid = (const int*)d_in[4];
    const float* coef = (const float*)d_in[5];
    const float* W1 = (const float*)d_in[6];
    const float* g1 = (const float*)d_in[7];
    const float* b1 = (const float*)d_in[8];
    const float* W2 = (const float*)d_in[9];
    const float* g2 = (const float*)d_in[10];
    const float* b2 = (const float*)d_in[11];
    const float* W3 = (const float*)d_in[12];
    const float* g3 = (const float*)d_in[13];
    const float* b3 = (const float*)d_in[14];

    float* out0 = (float*)d_out;
    float* out1 = out0 + (size_t)E_CNT * 128;
    float* out2 = out1 + (size_t)NG_CNT * 128;

    unsigned short* dws = (unsigned short*)d_ws;
    const size_t deltaElems = (size_t)E_CNT * 128;
    const size_t x2Elems = (size_t)NM_CNT * 256;
    const bool fast = ws_size >= (deltaElems + x2Elems) * sizeof(unsigned short);

    if (fast) {
        unsigned short* x2 = dws + deltaElems;
        mlp_kernel<384, 0, true><<<256, 1024, 0, stream>>>(
            gm, rect, mesh, pair, nullptr, W1, g1, b1, gm, out0, dws, E_CNT);
        mlp_kernel<128, 2, false><<<256, 1024, 0, stream>>>(
            rect, nullptr, nullptr, nullptr, nullptr, W3, g3, b3, rect, out1,
            nullptr, NG_CNT);
        agg_kernel<true><<<512, 256, 0, stream>>>(dws, nullptr, nullptr, mesh,
                                                  eid, coef, x2);
        mlp_kernel<256, 1, false><<<128, 256, 0, stream>>>(
            nullptr, nullptr, nullptr, nullptr, x2, W2, g2, b2, mesh, out2,
            nullptr, NM_CNT);
    } else {
        unsigned short* x2 = dws;  // needs only 4.2 MB
        mlp_kernel<384, 0, false><<<256, 1024, 0, stream>>>(
            gm, rect, mesh, pair, nullptr, W1, g1, b1, gm, out0, nullptr, E_CNT);
        mlp_kernel<128, 2, false><<<256, 1024, 0, stream>>>(
            rect, nullptr, nullptr, nullptr, nullptr, W3, g3, b3, rect, out1,
            nullptr, NG_CNT);
        agg_kernel<false><<<512, 256, 0, stream>>>(nullptr, out0, gm, mesh, eid,
                                                   coef, x2);
        mlp_kernel<256, 1, false><<<128, 256, 0, stream>>>(
            nullptr, nullptr, nullptr, nullptr, x2, W2, g2, b2, mesh, out2,
            nullptr, NM_CNT);
    }
}